// Round 4
// baseline (497.437 us; speedup 1.0000x reference)
//
#include <hip/hip_runtime.h>
#include <math.h>

#define Bn 512
#define Sn 1024
#define Tn 48

static constexpr float LOG2E = 1.4426950408889634f;
static constexpr float LN2f  = 0.6931471805599453f;

__device__ __forceinline__ float rlane(float x, int lane) {
  return __int_as_float(__builtin_amdgcn_readlane(__float_as_int(x), lane));
}
__device__ __forceinline__ float wave_max64(float v) {
  #pragma unroll
  for (int off = 32; off; off >>= 1) v = fmaxf(v, __shfl_xor(v, off));
  return v;
}

// One wave per batch, lane j owns state j (lanes 48..63 shadow state 47).
// Exp-domain forward scan: w_j = 2^(score_j - M). Per step:
//   w'_j = e_j * sum_i Ehat_ji * w_i,  Ehat = 2^(trans'-mtg) (constant),
//   e_j = 2^(em'_j) from prefetched emissions (off the critical chain).
// Renorm: exact 2^-E scaling measured stale (off-chain), folded into next
// chunk's e0. M recovers mtg via mask count at the end.
//
// Round-3 post-mortem: VGPR_Count=44 and ~190 VALU/step proved the compiler
// REMATERIALIZES E_i = exp2(fma(load,...)) per use inside the loop (48 v_exp
// at 8cy each = the 790cy/step). Fix: asm "+v" fences on all 48 E values
// INSIDE the loop body -> opaque loop-carried defs, remat impossible, must
// stay VGPR-resident.

#define DECL_E1(i) float E_##i = __builtin_amdgcn_exp2f(fmaf(trow[i], LOG2E, -mtg));
#define DECL_E_ALL \
  DECL_E1(0) DECL_E1(1) DECL_E1(2) DECL_E1(3) DECL_E1(4) DECL_E1(5) \
  DECL_E1(6) DECL_E1(7) DECL_E1(8) DECL_E1(9) DECL_E1(10) DECL_E1(11) \
  DECL_E1(12) DECL_E1(13) DECL_E1(14) DECL_E1(15) DECL_E1(16) DECL_E1(17) \
  DECL_E1(18) DECL_E1(19) DECL_E1(20) DECL_E1(21) DECL_E1(22) DECL_E1(23) \
  DECL_E1(24) DECL_E1(25) DECL_E1(26) DECL_E1(27) DECL_E1(28) DECL_E1(29) \
  DECL_E1(30) DECL_E1(31) DECL_E1(32) DECL_E1(33) DECL_E1(34) DECL_E1(35) \
  DECL_E1(36) DECL_E1(37) DECL_E1(38) DECL_E1(39) DECL_E1(40) DECL_E1(41) \
  DECL_E1(42) DECL_E1(43) DECL_E1(44) DECL_E1(45) DECL_E1(46) DECL_E1(47)

// In-loop residency fence: 12 read-write VGPR operands per asm (24 total
// operands, under the 30-operand limit), 4 blocks covering all 48.
#define FENCE12(a,b,c,d,e,f,g,h,i,j,k,l) \
  asm("" : "+v"(E_##a), "+v"(E_##b), "+v"(E_##c), "+v"(E_##d), \
           "+v"(E_##e), "+v"(E_##f), "+v"(E_##g), "+v"(E_##h), \
           "+v"(E_##i), "+v"(E_##j), "+v"(E_##k), "+v"(E_##l));
#define FENCE_E_ALL \
  FENCE12(0,1,2,3,4,5,6,7,8,9,10,11) \
  FENCE12(12,13,14,15,16,17,18,19,20,21,22,23) \
  FENCE12(24,25,26,27,28,29,30,31,32,33,34,35) \
  FENCE12(36,37,38,39,40,41,42,43,44,45,46,47)

#define ACC1(i,k) a##k = fmaf(rlane(w, i), E_##i, a##k);
#define ACC4(i0,i1,i2,i3) ACC1(i0,0) ACC1(i1,1) ACC1(i2,2) ACC1(i3,3)
#define ACC_ALL \
  ACC4(0,1,2,3)     ACC4(4,5,6,7)     ACC4(8,9,10,11)   ACC4(12,13,14,15) \
  ACC4(16,17,18,19) ACC4(20,21,22,23) ACC4(24,25,26,27) ACC4(28,29,30,31) \
  ACC4(32,33,34,35) ACC4(36,37,38,39) ACC4(40,41,42,43) ACC4(44,45,46,47)

__global__ __launch_bounds__(64, 1) void crf_fwd(
    const float* __restrict__ emissions,
    const int*   __restrict__ tags,
    const float* __restrict__ mask,
    const float* __restrict__ trans,
    const float* __restrict__ startt,
    const float* __restrict__ endt,
    float* __restrict__ per_batch)
{
  const int b  = blockIdx.x;
  const int j  = threadIdx.x;
  const int jc = (j < Tn) ? j : (Tn - 1);

  const float* __restrict__ emb = emissions + (size_t)b * Sn * Tn;
  const int*   __restrict__ tgb = tags + (size_t)b * Sn;
  const float* __restrict__ mkb = mask + (size_t)b * Sn;
  const float* __restrict__ trow = trans + jc * Tn;

  // Global max of transitions (log2 domain) for Ehat normalization.
  float mt = trow[0];
  #pragma unroll
  for (int i = 1; i < Tn; ++i) mt = fmaxf(mt, trow[i]);
  const float mtg = wave_max64(mt) * LOG2E;

  DECL_E_ALL   // Ehat row jc, values in (0,1]

  // Init (step 0).
  const float em0  = emb[jc];
  const int   tag0 = tgb[0];
  const float sc0  = (startt[jc] + em0) * LOG2E;
  const float m00  = wave_max64(sc0);
  float w = __builtin_amdgcn_exp2f(sc0 - m00);
  float M = m00;                       // accumulated log2 shift (mtg*cnt added at end)
  float numer = rlane(em0, tag0) + startt[tag0];   // lane-uniform, natural domain
  float cnt = 0.0f;
  int   lt  = tag0;

  auto do_step = [&](float em_raw, float e, float mk, int tg, float tval) {
    float a0 = 0.f, a1 = 0.f, a2 = 0.f, a3 = 0.f;
    ACC_ALL
    const float nxt = ((a0 + a1) + (a2 + a3)) * e;
    const bool on = (mk > 0.0f);
    w  = on ? nxt : w;
    numer = fmaf(mk, rlane(em_raw, tg) + tval, numer);
    cnt += mk;
    lt  = on ? tg : lt;
  };

  // Prologue: steps 1..3, unpipelined.
  #pragma unroll
  for (int s = 1; s < 4; ++s) {
    const float er = emb[s*Tn + jc];
    const float mk = mkb[s];
    const int   tg = tgb[s];
    const int   tp = tgb[s-1];
    const float tv = trans[tg*Tn + tp];
    const float e  = __builtin_amdgcn_exp2f(er * LOG2E);
    do_step(er, e, mk, tg, tv);
  }
  // First renorm measurement (applied to chunk s0=4's e0).
  float scale;
  {
    const float m = wave_max64(w);
    const int  mb = __float_as_int(m) & 0x7f800000;
    scale = __int_as_float(0x7f000000 - mb);    // exact 2^-E
    M += (float)((mb >> 23) - 127);
  }

  // Preload chunk s0 = 4.
  float ec0 = emb[4*Tn + jc], ec1 = emb[5*Tn + jc],
        ec2 = emb[6*Tn + jc], ec3 = emb[7*Tn + jc];
  int4   tgc = *(const int4*)(tgb + 4);
  float4 mkc = *(const float4*)(mkb + 4);
  float tv0, tv1, tv2, tv3;
  {
    const int ptail = tgb[3];
    tv0 = trans[tgc.x*Tn + ptail];
    tv1 = trans[tgc.y*Tn + tgc.x];
    tv2 = trans[tgc.z*Tn + tgc.y];
    tv3 = trans[tgc.w*Tn + tgc.z];
  }

  // Pipelined main loop: process chunk s0, prefetch chunk s0+4.
  for (int s0 = 4; s0 + 4 < Sn; s0 += 4) {
    FENCE_E_ALL   // opaque redef of all 48 E regs: remat/spill-per-use impossible

    const int sn = s0 + 4;
    const float en0 = emb[(sn+0)*Tn + jc];
    const float en1 = emb[(sn+1)*Tn + jc];
    const float en2 = emb[(sn+2)*Tn + jc];
    const float en3 = emb[(sn+3)*Tn + jc];
    const int4   tgn = *(const int4*)(tgb + sn);
    const float4 mkn = *(const float4*)(mkb + sn);

    const float e0 = __builtin_amdgcn_exp2f(ec0 * LOG2E) * scale;
    const float e1 = __builtin_amdgcn_exp2f(ec1 * LOG2E);
    const float e2 = __builtin_amdgcn_exp2f(ec2 * LOG2E);
    const float e3 = __builtin_amdgcn_exp2f(ec3 * LOG2E);

    do_step(ec0, e0, mkc.x, tgc.x, tv0);
    do_step(ec1, e1, mkc.y, tgc.y, tv1);
    const float mstale = wave_max64(w);      // stale max: off the critical chain
    do_step(ec2, e2, mkc.z, tgc.z, tv2);
    do_step(ec3, e3, mkc.w, tgc.w, tv3);

    {
      const int mb = __float_as_int(mstale) & 0x7f800000;
      scale = __int_as_float(0x7f000000 - mb);
      M += (float)((mb >> 23) - 127);
    }
    tv0 = trans[tgn.x*Tn + tgc.w];
    tv1 = trans[tgn.y*Tn + tgn.x];
    tv2 = trans[tgn.z*Tn + tgn.y];
    tv3 = trans[tgn.w*Tn + tgn.z];
    ec0 = en0; ec1 = en1; ec2 = en2; ec3 = en3;
    tgc = tgn; mkc = mkn;
  }
  // Tail chunk (steps 1020..1023), pending scale folded into e0.
  {
    const float e0 = __builtin_amdgcn_exp2f(ec0 * LOG2E) * scale;
    const float e1 = __builtin_amdgcn_exp2f(ec1 * LOG2E);
    const float e2 = __builtin_amdgcn_exp2f(ec2 * LOG2E);
    const float e3 = __builtin_amdgcn_exp2f(ec3 * LOG2E);
    do_step(ec0, e0, mkc.x, tgc.x, tv0);
    do_step(ec1, e1, mkc.y, tgc.y, tv1);
    do_step(ec2, e2, mkc.z, tgc.z, tv2);
    do_step(ec3, e3, mkc.w, tgc.w, tv3);
  }

  // Denominator: den = (M + mtg*cnt + log2(sum_j w_j * 2^(end'_j))) * ln2.
  float z = (j < Tn) ? w * __builtin_amdgcn_exp2f(endt[jc] * LOG2E) : 0.0f;
  #pragma unroll
  for (int off = 32; off; off >>= 1) z += __shfl_xor(z, off);
  const float den = (M + fmaf(mtg, cnt, __builtin_amdgcn_logf(z))) * LN2f;

  const float nm = numer + endt[lt];   // lane-uniform
  if (j == 0) per_batch[b] = den - nm;
}

__global__ __launch_bounds__(512) void reduce512(const float* __restrict__ pb,
                                                 float* __restrict__ out) {
  __shared__ float red[8];
  const int t = threadIdx.x;
  float v = pb[t];
  #pragma unroll
  for (int off = 32; off; off >>= 1) v += __shfl_xor(v, off);
  if ((t & 63) == 0) red[t >> 6] = v;
  __syncthreads();
  if (t == 0) {
    float s = 0.f;
    #pragma unroll
    for (int wv = 0; wv < 8; ++wv) s += red[wv];
    out[0] = s * (1.0f / 512.0f);
  }
}

extern "C" void kernel_launch(void* const* d_in, const int* in_sizes, int n_in,
                              void* d_out, int out_size, void* d_ws, size_t ws_size,
                              hipStream_t stream) {
  const float* emissions = (const float*)d_in[0];
  const int*   tags      = (const int*)d_in[1];
  const float* mask      = (const float*)d_in[2];
  const float* trans     = (const float*)d_in[3];
  const float* startt    = (const float*)d_in[4];
  const float* endt      = (const float*)d_in[5];
  float* pb = (float*)d_ws;   // 512 floats of scratch

  crf_fwd<<<Bn, 64, 0, stream>>>(emissions, tags, mask, trans, startt, endt, pb);
  reduce512<<<1, 512, 0, stream>>>(pb, (float*)d_out);
}

// Round 5
// 396.260 us; speedup vs baseline: 1.2553x; 1.2553x over previous
//
#include <hip/hip_runtime.h>
#include <math.h>

#define Bn 512
#define Sn 1024
#define Tn 48

typedef _Float16 half2v __attribute__((ext_vector_type(2)));

static constexpr float LOG2E = 1.4426950408889634f;
static constexpr float LN2f  = 0.6931471805599453f;
static constexpr float C6    = 0.015625f;   // 2^-6 per-step pre-scale (exact, tracked by 6*cnt)

#if defined(__has_builtin)
#  if __has_builtin(__builtin_amdgcn_fdot2)
#    define HAVE_FDOT2 1
#  endif
#endif
#ifndef HAVE_FDOT2
#  define HAVE_FDOT2 0
#endif

__device__ __forceinline__ float rlanef(float x, int lane) {
  return __int_as_float(__builtin_amdgcn_readlane(__float_as_int(x), lane));
}
__device__ __forceinline__ int rlanei(int x, int lane) {
  return __builtin_amdgcn_readlane(x, lane);
}

// DPP helpers (all-VALU cross-lane: no ds_swizzle/lgkm latency).
template <int CTRL>
__device__ __forceinline__ float dpp_mv_neginf(float x) {
  return __int_as_float(__builtin_amdgcn_update_dpp(
      (int)0xff800000, __float_as_int(x), CTRL, 0xf, 0xf, false));
}
// Full-wave max; result valid in lane 63 (standard ror1/2/4/8 + bcast15/31).
__device__ __forceinline__ float wave_redmax_lane63(float x) {
  x = fmaxf(x, dpp_mv_neginf<0x121>(x));  // row_ror:1
  x = fmaxf(x, dpp_mv_neginf<0x122>(x));  // row_ror:2
  x = fmaxf(x, dpp_mv_neginf<0x124>(x));  // row_ror:4
  x = fmaxf(x, dpp_mv_neginf<0x128>(x));  // row_ror:8
  x = fmaxf(x, dpp_mv_neginf<0x142>(x));  // row_bcast:15
  x = fmaxf(x, dpp_mv_neginf<0x143>(x));  // row_bcast:31
  return x;
}
__device__ __forceinline__ float wave_max_all(float x) {
  return rlanef(wave_redmax_lane63(x), 63);
}

// 24 packed f16x2 registers holding Ehat row jc (half the footprint of 48 f32
// — rounds 2-4 proved the allocator will not hold 48 + state; 24 fits).
#define DECL_P1(k) \
  half2v P_##k; { \
    const float e0_ = __builtin_amdgcn_exp2f(fmaf(trow[2*(k)],   LOG2E, -mtg)); \
    const float e1_ = __builtin_amdgcn_exp2f(fmaf(trow[2*(k)+1], LOG2E, -mtg)); \
    P_##k[0] = (_Float16)e0_; P_##k[1] = (_Float16)e1_; }
#define DECL_P_ALL \
  DECL_P1(0)  DECL_P1(1)  DECL_P1(2)  DECL_P1(3)  DECL_P1(4)  DECL_P1(5) \
  DECL_P1(6)  DECL_P1(7)  DECL_P1(8)  DECL_P1(9)  DECL_P1(10) DECL_P1(11) \
  DECL_P1(12) DECL_P1(13) DECL_P1(14) DECL_P1(15) DECL_P1(16) DECL_P1(17) \
  DECL_P1(18) DECL_P1(19) DECL_P1(20) DECL_P1(21) DECL_P1(22) DECL_P1(23)

#if HAVE_FDOT2
#define DOT1(k, a) { const int pk_ = rlanei(hpk, 2*(k)); \
  a = __builtin_amdgcn_fdot2(P_##k, __builtin_bit_cast(half2v, pk_), a, false); }
#else
#define DOT1(k, a) { const int pk_ = rlanei(hpk, 2*(k)); \
  const half2v hb_ = __builtin_bit_cast(half2v, pk_); \
  a = fmaf((float)P_##k[0], (float)hb_[0], fmaf((float)P_##k[1], (float)hb_[1], a)); }
#endif
#define DOT4(k0,k1,k2,k3) DOT1(k0,a0) DOT1(k1,a1) DOT1(k2,a2) DOT1(k3,a3)
#define DOT_ALL \
  DOT4(0,1,2,3)     DOT4(4,5,6,7)     DOT4(8,9,10,11) \
  DOT4(12,13,14,15) DOT4(16,17,18,19) DOT4(20,21,22,23)

__global__ __launch_bounds__(64, 1)
__attribute__((amdgpu_waves_per_eu(1)))
void crf_fwd(
    const float* __restrict__ emissions,
    const int*   __restrict__ tags,
    const float* __restrict__ mask,
    const float* __restrict__ trans,
    const float* __restrict__ startt,
    const float* __restrict__ endt,
    float* __restrict__ per_batch)
{
  const int b  = blockIdx.x;
  const int j  = threadIdx.x;
  const int jc = (j < Tn) ? j : (Tn - 1);

  const float* __restrict__ emb  = emissions + (size_t)b * Sn * Tn;
  const int*   __restrict__ tgb  = tags + (size_t)b * Sn;
  const float* __restrict__ mkb  = mask + (size_t)b * Sn;
  const float* __restrict__ trow = trans + jc * Tn;

  // Global max of transitions (log2 domain) for Ehat normalization.
  float mt = trow[0];
  #pragma unroll
  for (int i = 1; i < Tn; ++i) mt = fmaxf(mt, trow[i]);
  const float mtg = wave_max_all(mt) * LOG2E;

  DECL_P_ALL

  // Init (step 0), exp domain: w_j = 2^(score_j - M).
  const float em0  = emb[jc];
  const int   tag0 = tgb[0];
  const float sc0  = (startt[jc] + em0) * LOG2E;
  const float m00  = wave_max_all(sc0);
  float w = __builtin_amdgcn_exp2f(sc0 - m00);
  float M = m00;
  float numer = rlanef(em0, tag0) + startt[tag0];
  float cnt = 0.0f;
  int   lt  = tag0;
  int   hpk = 0;   // packed f16 (w_2k, w_2k+1) at even lanes

  auto repack = [&]() {
    const float wn = __int_as_float(__builtin_amdgcn_update_dpp(
        0, __float_as_int(w), 0x111 /*row_shr:1*/, 0xf, 0xf, true));
    half2v hp; hp[0] = (_Float16)w; hp[1] = (_Float16)wn;
    hpk = __builtin_bit_cast(int, hp);
  };

  auto do_step = [&](float em_raw, float e6, float mk, int tg, float tval) {
    float a0 = 0.f, a1 = 0.f, a2 = 0.f, a3 = 0.f;
    DOT_ALL
    const float nxt = ((a0 + a1) + (a2 + a3)) * e6;
    const bool on = (mk > 0.0f);
    w = on ? nxt : w;
    numer = fmaf(mk, rlanef(em_raw, tg) + tval, numer);
    cnt += mk;
    lt = on ? tg : lt;
  };

  // Exact power-of-2 renorm: measure (DPP max -> uniform scale), apply later.
  float pendS = 1.0f, pendM = 0.0f;
  auto measure = [&](float& S, float& A) {
    const float mx = wave_redmax_lane63(w);
    const int ms = rlanei(__float_as_int(mx), 63);
    const int mb = ms & 0x7f800000;
    S = __int_as_float(0x7f000000 - mb);   // exact 2^-E (uniform)
    A = (float)((mb >> 23) - 127);
  };

  repack();

  // Prologue: steps 1..3 (apply cadence: odd steps; measure 2 steps ahead).
  float scA = 1.0f, mA = 0.0f;
  {
    // step 1
    {
      const float er = emb[1*Tn + jc];
      const float e6 = __builtin_amdgcn_exp2f(er * LOG2E) * C6;
      do_step(er, e6, mkb[1], tgb[1], trans[tgb[1]*Tn + tgb[0]]);
      measure(scA, mA);            // applied at step 3
      repack();
    }
    // step 2
    {
      const float er = emb[2*Tn + jc];
      const float e6 = __builtin_amdgcn_exp2f(er * LOG2E) * C6;
      do_step(er, e6, mkb[2], tgb[2], trans[tgb[2]*Tn + tgb[1]]);
      repack();
    }
    // step 3
    {
      const float er = emb[3*Tn + jc];
      const float e6 = __builtin_amdgcn_exp2f(er * LOG2E) * C6;
      do_step(er, e6, mkb[3], tgb[3], trans[tgb[3]*Tn + tgb[2]]);
      w *= scA; M += mA;
      measure(pendS, pendM);       // applied at step 5 (first chunk's s0+1)
      repack();
    }
  }

  // Preload chunk s0 = 4.
  float ec0 = emb[4*Tn + jc], ec1 = emb[5*Tn + jc],
        ec2 = emb[6*Tn + jc], ec3 = emb[7*Tn + jc];
  int4   tgc = *(const int4*)(tgb + 4);
  float4 mkc = *(const float4*)(mkb + 4);
  float tv0, tv1, tv2, tv3;
  {
    const int ptail = tgb[3];
    tv0 = trans[tgc.x*Tn + ptail];
    tv1 = trans[tgc.y*Tn + tgc.x];
    tv2 = trans[tgc.z*Tn + tgc.y];
    tv3 = trans[tgc.w*Tn + tgc.z];
  }

  // Main loop: chunk of 4 steps; renorm applied at s0+1 and s0+3 (stale by 2,
  // DPP-only measurement overlaps the dot issue stream).
  for (int s0 = 4; s0 + 4 < Sn; s0 += 4) {
    const int sn = s0 + 4;
    const float en0 = emb[(sn+0)*Tn + jc];
    const float en1 = emb[(sn+1)*Tn + jc];
    const float en2 = emb[(sn+2)*Tn + jc];
    const float en3 = emb[(sn+3)*Tn + jc];
    const int4   tgn = *(const int4*)(tgb + sn);
    const float4 mkn = *(const float4*)(mkb + sn);

    const float e60 = __builtin_amdgcn_exp2f(ec0 * LOG2E) * C6;
    const float e61 = __builtin_amdgcn_exp2f(ec1 * LOG2E) * C6;
    const float e62 = __builtin_amdgcn_exp2f(ec2 * LOG2E) * C6;
    const float e63 = __builtin_amdgcn_exp2f(ec3 * LOG2E) * C6;

    do_step(ec0, e60, mkc.x, tgc.x, tv0);
    repack();
    do_step(ec1, e61, mkc.y, tgc.y, tv1);
    w *= pendS; M += pendM;
    measure(scA, mA);
    repack();
    do_step(ec2, e62, mkc.z, tgc.z, tv2);
    repack();
    do_step(ec3, e63, mkc.w, tgc.w, tv3);
    w *= scA; M += mA;
    measure(pendS, pendM);
    repack();

    tv0 = trans[tgn.x*Tn + tgc.w];
    tv1 = trans[tgn.y*Tn + tgn.x];
    tv2 = trans[tgn.z*Tn + tgn.y];
    tv3 = trans[tgn.w*Tn + tgn.z];
    ec0 = en0; ec1 = en1; ec2 = en2; ec3 = en3;
    tgc = tgn; mkc = mkn;
  }
  // Tail chunk (steps 1020..1023).
  {
    const float e60 = __builtin_amdgcn_exp2f(ec0 * LOG2E) * C6;
    const float e61 = __builtin_amdgcn_exp2f(ec1 * LOG2E) * C6;
    const float e62 = __builtin_amdgcn_exp2f(ec2 * LOG2E) * C6;
    const float e63 = __builtin_amdgcn_exp2f(ec3 * LOG2E) * C6;
    do_step(ec0, e60, mkc.x, tgc.x, tv0);
    repack();
    do_step(ec1, e61, mkc.y, tgc.y, tv1);
    w *= pendS; M += pendM;
    measure(scA, mA);
    repack();
    do_step(ec2, e62, mkc.z, tgc.z, tv2);
    repack();
    do_step(ec3, e63, mkc.w, tgc.w, tv3);
    w *= scA; M += mA;
  }

  // den = (M + (mtg + 6)*cnt + log2(sum_j w_j * 2^(end'_j))) * ln2.
  float z = (j < Tn) ? w * __builtin_amdgcn_exp2f(endt[jc] * LOG2E) : 0.0f;
  #pragma unroll
  for (int off = 32; off; off >>= 1) z += __shfl_xor(z, off);
  const float den = (M + (mtg + 6.0f) * cnt + __builtin_amdgcn_logf(z)) * LN2f;

  const float nm = numer + endt[lt];
  if (j == 0) per_batch[b] = den - nm;
}

__global__ __launch_bounds__(512) void reduce512(const float* __restrict__ pb,
                                                 float* __restrict__ out) {
  __shared__ float red[8];
  const int t = threadIdx.x;
  float v = pb[t];
  #pragma unroll
  for (int off = 32; off; off >>= 1) v += __shfl_xor(v, off);
  if ((t & 63) == 0) red[t >> 6] = v;
  __syncthreads();
  if (t == 0) {
    float s = 0.f;
    #pragma unroll
    for (int wv = 0; wv < 8; ++wv) s += red[wv];
    out[0] = s * (1.0f / 512.0f);
  }
}

extern "C" void kernel_launch(void* const* d_in, const int* in_sizes, int n_in,
                              void* d_out, int out_size, void* d_ws, size_t ws_size,
                              hipStream_t stream) {
  const float* emissions = (const float*)d_in[0];
  const int*   tags      = (const int*)d_in[1];
  const float* mask      = (const float*)d_in[2];
  const float* trans     = (const float*)d_in[3];
  const float* startt    = (const float*)d_in[4];
  const float* endt      = (const float*)d_in[5];
  float* pb = (float*)d_ws;   // 512 floats of scratch

  crf_fwd<<<Bn, 64, 0, stream>>>(emissions, tags, mask, trans, startt, endt, pb);
  reduce512<<<1, 512, 0, stream>>>(pb, (float*)d_out);
}